// Round 8
// baseline (2664.658 us; speedup 1.0000x reference)
//
#include <hip/hip_runtime.h>
#include <hip/hip_bf16.h>
#include <hip/hip_fp16.h>
#include <float.h>
#include <limits.h>

#define NROWS 131072
#define DIM   256
#define NLVL  4
#define KC    1024
#define MARGIN 7.0f     // 6 (validated) + 1 fp16/RTN slack
#define CAP   64

typedef __attribute__((ext_vector_type(8))) short bf16x8;
typedef __attribute__((ext_vector_type(4))) float f32x4;
typedef __attribute__((ext_vector_type(4))) unsigned short us4;

__device__ __forceinline__ unsigned short f2b(float f){
  __hip_bfloat16 h = __float2bfloat16(f);
  return *reinterpret_cast<unsigned short*>(&h);
}

__device__ __forceinline__ float sqb(float x){
  float s = x * x;
  asm volatile("" : "+v"(s));
  return s;
}

// ---------------- prep kernels (validated r4-r7) ------------------------
__global__ void prep_cbb(const float* __restrict__ cb, unsigned short* __restrict__ cbb){
  const int wave = threadIdx.x >> 6, lane = threadIdx.x & 63;
  const int c = blockIdx.x * 4 + wave;
  const size_t off = (size_t)c * DIM + lane * 4;
  const float4 v = *reinterpret_cast<const float4*>(cb + off);
  us4 u = { f2b(v.x), f2b(v.y), f2b(v.z), f2b(v.w) };
  *reinterpret_cast<us4*>(cbb + off) = u;
}

__global__ void prep_cn(const float* __restrict__ cb, float* __restrict__ cnx){
  const int c = blockIdx.x * 64 + threadIdx.x;
  const float* p = cb + (size_t)c * DIM;
  float blk[2];
  for (int b = 0; b < 2; ++b){
    float r[8];
#pragma unroll
    for (int j = 0; j < 8; ++j) r[j] = sqb(p[b*128 + j]);
    for (int i = 8; i < 128; i += 8)
#pragma unroll
      for (int j = 0; j < 8; ++j) r[j] += sqb(p[b*128 + i + j]);
    blk[b] = ((r[0]+r[1]) + (r[2]+r[3])) + ((r[4]+r[5]) + (r[6]+r[7]));
  }
  cnx[c] = blk[0] + blk[1];
}

// ---------------- K1: LDS-tiled GEMM + g8-min epilogue ------------------
// 64 rows/block, 8 waves (2 rowG x 4 colG), wave tile 32 rows x 64 centers.
// B (residual rows, bf16) built once in LDS; A (codebook) reg-staged into
// double-buffered LDS tiles of 256 centers x 32 k. Scores -> g8min -> global.
template<int LVL>
__global__ __launch_bounds__(512, 4)
void rvq_score(const float* __restrict__ feat,
               const float* __restrict__ cb32,
               const unsigned short* __restrict__ cbb_l,
               const float* __restrict__ cnx_l,
               const int* __restrict__ idxw,
               unsigned short* __restrict__ g8buf)
{
  __shared__ unsigned short Bs[64 * 256];        // 32 KB, chunk ^ (row&7) swizzle
  __shared__ unsigned short As[2][256 * 32];     // 2 x 16 KB, chunk ^ (row&3) swizzle
  __shared__ unsigned short g8s[64 * 128];       // 16 KB, col ^ ((row&7)<<3) swizzle

  const int tid  = threadIdx.x;
  const int lane = tid & 63;
  const int wave = tid >> 6;
  const int r16  = lane & 15, quad = lane >> 4;
  const int wr   = wave >> 2, wc = wave & 3;     // 2 x 4
  const int rowbase = (int)blockIdx.x * 64;

  // ---- A tile reg-stage load (tile = (ct,kt), 256x32 bf16) --------------
  bf16x8 s0, s1;
  {
    // tile 0 issued early; overlaps B build
    const int ct = 0, kt = 0;
#pragma unroll
    for (int it = 0; it < 2; ++it){
      const int i = it*512 + tid, r = i >> 2, c = i & 3;
      const bf16x8 v = *reinterpret_cast<const bf16x8*>(
          cbb_l + (size_t)(ct*256 + r) * DIM + kt*32 + ((c ^ (r & 3)) << 3));
      if (it == 0) s0 = v; else s1 = v;
    }
  }

  // ---- phase 0: build residual rows in LDS (exact fp32 chain -> bf16) ---
  {
    const int row = tid >> 3;                    // 0..63
    const int d0 = (tid & 7) * 32;
    const int grow = rowbase + row;
    int hist[NLVL > 1 ? NLVL : 1];
#pragma unroll
    for (int j = 0; j < LVL; ++j) hist[j] = idxw[j * NROWS + grow];
#pragma unroll
    for (int c4 = 0; c4 < 4; ++c4){
      const int d = d0 + c4*8;
      const float* p = feat + (size_t)grow * DIM + d;
      float4 f0 = *reinterpret_cast<const float4*>(p);
      float4 f1 = *reinterpret_cast<const float4*>(p + 4);
#pragma unroll
      for (int j = 0; j < LVL; ++j){
        const float* cp = cb32 + ((size_t)j * KC + hist[j]) * DIM + d;
        const float4 c0 = *reinterpret_cast<const float4*>(cp);
        const float4 c1 = *reinterpret_cast<const float4*>(cp + 4);
        f0.x -= c0.x; f0.y -= c0.y; f0.z -= c0.z; f0.w -= c0.w;
        f1.x -= c1.x; f1.y -= c1.y; f1.z -= c1.z; f1.w -= c1.w;
      }
      bf16x8 b;
      b[0]=(short)f2b(f0.x); b[1]=(short)f2b(f0.y); b[2]=(short)f2b(f0.z); b[3]=(short)f2b(f0.w);
      b[4]=(short)f2b(f1.x); b[5]=(short)f2b(f1.y); b[6]=(short)f2b(f1.z); b[7]=(short)f2b(f1.w);
      *reinterpret_cast<bf16x8*>(&Bs[row*256 + (((d >> 3) ^ (row & 7)) << 3)]) = b;
    }
  }

  f32x4 acc[2][4];
#pragma unroll
  for (int mi = 0; mi < 2; ++mi)
#pragma unroll
    for (int ni = 0; ni < 4; ++ni) acc[mi][ni] = (f32x4){0.f,0.f,0.f,0.f};

  int buf = 0;
  for (int i = 0; i < 32; ++i){
    const int ct = i >> 3, kt = i & 7;
    __syncthreads();                             // prior readers of As[buf] done; Bs ready (i==0)
    // commit staged regs -> As[buf]
    {
      const int i0 = tid, r0 = i0 >> 2, c0 = i0 & 3;
      *reinterpret_cast<bf16x8*>(&As[buf][r0*32 + (c0 << 3)]) = s0;
      const int i1 = 512 + tid, r1 = i1 >> 2, c1 = i1 & 3;
      *reinterpret_cast<bf16x8*>(&As[buf][r1*32 + (c1 << 3)]) = s1;
    }
    // issue next tile's loads (overlap with MFMA below)
    if (i < 31){
      const int ni2 = i + 1, nct = ni2 >> 3, nkt = ni2 & 7;
#pragma unroll
      for (int it = 0; it < 2; ++it){
        const int ii = it*512 + tid, r = ii >> 2, c = ii & 3;
        const bf16x8 v = *reinterpret_cast<const bf16x8*>(
            cbb_l + (size_t)(nct*256 + r) * DIM + nkt*32 + ((c ^ (r & 3)) << 3));
        if (it == 0) s0 = v; else s1 = v;
      }
    }
    __syncthreads();                             // As[buf] visible

    // ---- compute tile (ct,kt): 8 MFMAs per wave ------------------------
    bf16x8 Bf[2], Af[4];
#pragma unroll
    for (int mi = 0; mi < 2; ++mi){
      const int row = wr*32 + mi*16 + r16;
      Bf[mi] = *reinterpret_cast<const bf16x8*>(
          &Bs[row*256 + (((kt*4 + quad) ^ (row & 7)) << 3)]);
    }
#pragma unroll
    for (int ni = 0; ni < 4; ++ni){
      const int arow = wc*64 + ni*16 + r16;
      Af[ni] = *reinterpret_cast<const bf16x8*>(
          &As[buf][arow*32 + ((quad ^ (arow & 3)) << 3)]);
    }
#pragma unroll
    for (int ni = 0; ni < 4; ++ni){
      acc[0][ni] = __builtin_amdgcn_mfma_f32_16x16x32_bf16(Af[ni], Bf[0], acc[0][ni], 0, 0, 0);
      acc[1][ni] = __builtin_amdgcn_mfma_f32_16x16x32_bf16(Af[ni], Bf[1], acc[1][ni], 0, 0, 0);
    }

    // ---- per-sweep epilogue: scores -> g8min -> LDS --------------------
    if (kt == 7){
#pragma unroll
      for (int mi = 0; mi < 2; ++mi)
#pragma unroll
        for (int ni = 0; ni < 4; ++ni){
          const int c0 = ct*256 + wc*64 + ni*16 + quad*4;
          const float4 cn = *reinterpret_cast<const float4*>(cnx_l + c0);
          const f32x4 a = acc[mi][ni];
          const float m4 = fminf(fminf(cn.x - 2.f*a[0], cn.y - 2.f*a[1]),
                                 fminf(cn.z - 2.f*a[2], cn.w - 2.f*a[3]));
          const float m8 = fminf(m4, __shfl_xor(m4, 16));
          if ((quad & 1) == 0){
            const int row = wr*32 + mi*16 + r16;
            const int col = c0 >> 3;
            const __half h = __float2half(m8);
            g8s[row*128 + (col ^ ((row & 7) << 3))] =
                __builtin_bit_cast(unsigned short, h);
          }
          acc[mi][ni] = (f32x4){0.f,0.f,0.f,0.f};
        }
    }
    buf ^= 1;
  }

  __syncthreads();
  // ---- coalesced g8 write-out: 64 rows x 256B --------------------------
#pragma unroll
  for (int it = 0; it < 2; ++it){
    const int i = it*512 + tid;
    const int row = i >> 4, ch = i & 15;
    const uint4 v = *reinterpret_cast<const uint4*>(
        &g8s[row*128 + ((ch*8) ^ ((row & 7) << 3))]);
    *reinterpret_cast<uint4*>(g8buf + (size_t)(rowbase + row)*128 + ch*8) = v;
  }
}

// ---------------- K2: selection + exact np-fp32 re-rank (validated) -----
// 16 lanes/row; read g8 row, thr = min+MARGIN, flagged g8 -> 8-center
// candidates; exact fp32-chain residual + fmaf-chain dots; tie-break lowest.
template<int LVL>
__global__ __launch_bounds__(256)
void rvq_rerank(const float* __restrict__ feat,
                const float* __restrict__ cb32,
                const float* __restrict__ cnx_l,
                int* __restrict__ idxw,
                const unsigned short* __restrict__ g8buf)
{
  __shared__ float rres[16][260];
  __shared__ int rcnt[16];
  __shared__ int rcand[16][CAP];
  const int tid = threadIdx.x;
  const int g = tid >> 4, q = tid & 15;
  const float* cbl = cb32 + (size_t)LVL * KC * DIM;

  for (int grow = blockIdx.x * 16 + g; grow < NROWS; grow += gridDim.x * 16){
    if (q == 0) rcnt[g] = 0;

    // ---- read 8 g8-mins, row min, threshold ----------------------------
    const uint4 u = *reinterpret_cast<const uint4*>(g8buf + (size_t)grow*128 + q*8);
    const unsigned uu[4] = { u.x, u.y, u.z, u.w };
    float v[8];
#pragma unroll
    for (int e = 0; e < 8; ++e){
      const unsigned short hv = (unsigned short)(uu[e >> 1] >> ((e & 1) * 16));
      v[e] = __half2float(__builtin_bit_cast(__half, hv));
    }
    float mn = v[0];
#pragma unroll
    for (int e = 1; e < 8; ++e) mn = fminf(mn, v[e]);
#pragma unroll
    for (int m = 1; m < 16; m <<= 1) mn = fminf(mn, __shfl_xor(mn, m));
    const float thr = mn + MARGIN;

    // ---- candidate supersets: flagged g8 -> its 8 centers ---------------
#pragma unroll
    for (int e = 0; e < 8; ++e){
      if (v[e] <= thr){
        const int pos = atomicAdd(&rcnt[g], 8);
        const int base = (q*8 + e) * 8;
#pragma unroll
        for (int e2 = 0; e2 < 8; ++e2)
          if (pos + e2 < CAP) rcand[g][pos + e2] = base + e2;
      }
    }

    // ---- exact fp32-chain residual (lane q owns d = q*16..q*16+15) ------
#pragma unroll
    for (int i4 = 0; i4 < 4; ++i4){
      const int d = q*16 + i4*4;
      float4 w = *reinterpret_cast<const float4*>(feat + (size_t)grow * DIM + d);
#pragma unroll
      for (int j2 = 0; j2 < LVL; ++j2){
        const int kj = idxw[(size_t)j2 * NROWS + grow];
        const float4 cv = *reinterpret_cast<const float4*>(
            cb32 + ((size_t)j2 * KC + kj) * DIM + d);
        w.x -= cv.x; w.y -= cv.y; w.z -= cv.z; w.w -= cv.w;
      }
      *reinterpret_cast<float4*>(&rres[g][d]) = w;
    }

    const int c = rcnt[g];
    float bs = FLT_MAX; int bi = INT_MAX;
    if (c <= CAP){
      for (int qq = q; qq < c; qq += 16){
        const int ci = rcand[g][qq];
        float a = 0.f;
        for (int d4 = 0; d4 < 64; ++d4){
          const float4 cv = *reinterpret_cast<const float4*>(cbl + (size_t)ci * DIM + d4*4);
          const float4 rv = *reinterpret_cast<const float4*>(&rres[g][d4*4]);
          a = fmaf(rv.x, cv.x, a); a = fmaf(rv.y, cv.y, a);
          a = fmaf(rv.z, cv.z, a); a = fmaf(rv.w, cv.w, a);
        }
        const float sc = cnx_l[ci] - 2.0f * a;
        if (sc < bs || (sc == bs && ci < bi)){ bs = sc; bi = ci; }
      }
    } else {
      for (int t = 0; t < 64; ++t){
        const int ci = q + 16*t;
        float a = 0.f;
        for (int d4 = 0; d4 < 64; ++d4){
          const float4 cv = *reinterpret_cast<const float4*>(cbl + (size_t)ci * DIM + d4*4);
          const float4 rv = *reinterpret_cast<const float4*>(&rres[g][d4*4]);
          a = fmaf(rv.x, cv.x, a); a = fmaf(rv.y, cv.y, a);
          a = fmaf(rv.z, cv.z, a); a = fmaf(rv.w, cv.w, a);
        }
        const float sc = cnx_l[ci] - 2.0f * a;
        if (sc < bs){ bs = sc; bi = ci; }
      }
    }
#pragma unroll
    for (int m = 1; m < 16; m <<= 1){
      const float ob = __shfl_xor(bs, m); const int oi = __shfl_xor(bi, m);
      if (ob < bs || (ob == bs && oi < bi)){ bs = ob; bi = oi; }
    }
    if (q == 0) idxw[(size_t)LVL * NROWS + grow] = bi;
  }
}

// ---------------- K3: final output = q0+q1+q2+q3 (validated r5-r7) ------
__global__ __launch_bounds__(256)
void rvq_out(const float* __restrict__ cb32,
             const int* __restrict__ idxw,
             float* __restrict__ out)
{
  const int tid = threadIdx.x;
  const int row = tid >> 4, sub = tid & 15;
  const size_t n = (size_t)blockIdx.x * 16 + row;
  int hist[NLVL];
#pragma unroll
  for (int j2 = 0; j2 < 4; ++j2) hist[j2] = idxw[(size_t)j2 * NROWS + n];
#pragma unroll
  for (int i = 0; i < 4; ++i){
    const int d = sub*4 + i*64;
    float4 a = *reinterpret_cast<const float4*>(
        cb32 + ((size_t)0 * KC + hist[0]) * DIM + d);
#pragma unroll
    for (int j2 = 1; j2 < 4; ++j2){
      const float4 qv = *reinterpret_cast<const float4*>(
          cb32 + ((size_t)j2 * KC + hist[j2]) * DIM + d);
      a.x += qv.x; a.y += qv.y; a.z += qv.z; a.w += qv.w;
    }
    *reinterpret_cast<float4*>(out + n*DIM + d) = a;
  }
}

extern "C" void kernel_launch(void* const* d_in, const int* in_sizes, int n_in,
                              void* d_out, int out_size, void* d_ws, size_t ws_size,
                              hipStream_t stream){
  const float* feat = (const float*)d_in[0];
  const float* cb32 = (const float*)d_in[1];
  float* out = (float*)d_out;

  char* ws = (char*)d_ws;
  float* cnx = (float*)(ws);                                  // 16 KB
  unsigned short* cbb  = (unsigned short*)(ws + 16384);       // 2 MB
  int*   idxw = (int*)(ws + 16384 + 2097152);                 // 2 MB
  unsigned short* g8buf = (unsigned short*)(ws + 16384 + 2097152 + 2097152); // 33.5 MB

  prep_cbb<<<1024, 256, 0, stream>>>(cb32, cbb);
  prep_cn<<<64, 64, 0, stream>>>(cb32, cnx);

#define LVL_STEP(L) \
  rvq_score<L><<<2048, 512, 0, stream>>>(feat, cb32, cbb + (size_t)L*KC*DIM, \
      cnx + L*KC, idxw, g8buf); \
  rvq_rerank<L><<<1024, 256, 0, stream>>>(feat, cb32, cnx + L*KC, idxw, g8buf);

  LVL_STEP(0)
  LVL_STEP(1)
  LVL_STEP(2)
  LVL_STEP(3)
#undef LVL_STEP

  rvq_out<<<8192, 256, 0, stream>>>(cb32, idxw, out);
}

// Round 9
// 2159.746 us; speedup vs baseline: 1.2338x; 1.2338x over previous
//
#include <hip/hip_runtime.h>
#include <hip/hip_bf16.h>
#include <hip/hip_fp16.h>
#include <float.h>
#include <limits.h>

#define NROWS 131072
#define DIM   256
#define NLVL  4
#define KC    1024
#define AMB_MARGIN 6.0f  // fp32 ambiguity test (validated r4-r8)
#define MARGIN 7.0f      // g8 expansion: 6 + 1 fp16/RTN slack (validated r8)
#define CAP   64

typedef __attribute__((ext_vector_type(8))) short bf16x8;
typedef __attribute__((ext_vector_type(4))) float f32x4;
typedef __attribute__((ext_vector_type(4))) unsigned short us4;

__device__ __forceinline__ unsigned short f2b(float f){
  __hip_bfloat16 h = __float2bfloat16(f);
  return *reinterpret_cast<unsigned short*>(&h);
}

__device__ __forceinline__ float sqb(float x){
  float s = x * x;
  asm volatile("" : "+v"(s));
  return s;
}

// running top-2 update (processing order has ascending ci per lane)
__device__ __forceinline__ void upd2(float& m1, int& i1, float& m2, float s, int ci){
  const bool lt = s < m1;
  m2 = lt ? m1 : fminf(m2, s);
  i1 = lt ? ci : i1;
  m1 = lt ? s : m1;
}

// merge two top-2 triples (first-index preference on ties)
__device__ __forceinline__ void merge2(float& m1, int& i1, float& m2,
                                       float om1, int oi1, float om2){
  if (om1 < m1 || (om1 == m1 && oi1 < i1)){
    m2 = fminf(m1, om2); m1 = om1; i1 = oi1;
  } else {
    m2 = fminf(m2, om1);
  }
}

// ---------------- prep kernels (validated r4-r8) ------------------------
__global__ void zero4(int* __restrict__ p){
  if (threadIdx.x < 4) p[threadIdx.x] = 0;
}

__global__ void prep_cbb(const float* __restrict__ cb, unsigned short* __restrict__ cbb){
  const int wave = threadIdx.x >> 6, lane = threadIdx.x & 63;
  const int c = blockIdx.x * 4 + wave;
  const size_t off = (size_t)c * DIM + lane * 4;
  const float4 v = *reinterpret_cast<const float4*>(cb + off);
  us4 u = { f2b(v.x), f2b(v.y), f2b(v.z), f2b(v.w) };
  *reinterpret_cast<us4*>(cbb + off) = u;
}

__global__ void prep_cn(const float* __restrict__ cb, float* __restrict__ cnx){
  const int c = blockIdx.x * 64 + threadIdx.x;
  const float* p = cb + (size_t)c * DIM;
  float blk[2];
  for (int b = 0; b < 2; ++b){
    float r[8];
#pragma unroll
    for (int j = 0; j < 8; ++j) r[j] = sqb(p[b*128 + j]);
    for (int i = 8; i < 128; i += 8)
#pragma unroll
      for (int j = 0; j < 8; ++j) r[j] += sqb(p[b*128 + i + j]);
    blk[b] = ((r[0]+r[1]) + (r[2]+r[3])) + ((r[4]+r[5]) + (r[6]+r[7]));
  }
  cnx[c] = blk[0] + blk[1];
}

// ---------------- K1: LDS-tiled GEMM + g8min + top-2 classify -----------
// 64 rows/block, 8 waves (2x4), wave tile 32 rows x 64 centers (r8 GEMM,
// validated). New: per-row fp32 top-2 -> unambiguous rows finish here.
template<int LVL>
__global__ __launch_bounds__(512, 4)
void rvq_score(const float* __restrict__ feat,
               const float* __restrict__ cb32,
               const unsigned short* __restrict__ cbb_l,
               const float* __restrict__ cnx_l,
               int* __restrict__ idxw,
               unsigned short* __restrict__ g8buf,
               int* __restrict__ ambcnt,
               int* __restrict__ ambrows)
{
  __shared__ __align__(16) char smem[81920];
  unsigned short* Bs  = (unsigned short*)smem;            // 32 KB
  unsigned short* As  = (unsigned short*)(smem + 32768);  // 32 KB (2 bufs)
  unsigned short* g8s = (unsigned short*)(smem + 65536);  // 16 KB
  // aliases into As region (free after main loop):
  float* wm1 = (float*)(smem + 32768);                    // [64*4]
  int*   wi1 = (int*)  (smem + 32768 + 1024);
  float* wm2 = (float*)(smem + 32768 + 2048);
  int*   alist = (int*)(smem + 32768 + 3072);             // [64]
  int*   acnt_s = (int*)(smem + 32768 + 3328);
  int*   abase_s = (int*)(smem + 32768 + 3344);

  const int tid  = threadIdx.x;
  const int lane = tid & 63;
  const int wave = tid >> 6;
  const int r16  = lane & 15, quad = lane >> 4;
  const int wr   = wave >> 2, wc = wave & 3;
  const int rowbase = (int)blockIdx.x * 64;

  // ---- A tile 0 reg-stage (overlaps B build) ---------------------------
  bf16x8 s0, s1;
  {
#pragma unroll
    for (int it = 0; it < 2; ++it){
      const int i = it*512 + tid, r = i >> 2, c = i & 3;
      const bf16x8 v = *reinterpret_cast<const bf16x8*>(
          cbb_l + (size_t)r * DIM + ((c ^ (r & 3)) << 3));
      if (it == 0) s0 = v; else s1 = v;
    }
  }

  // ---- phase 0: residual rows -> LDS (exact fp32 chain -> bf16) --------
  {
    const int row = tid >> 3;
    const int d0 = (tid & 7) * 32;
    const int grow = rowbase + row;
    int hist[NLVL > 1 ? NLVL : 1];
#pragma unroll
    for (int j = 0; j < LVL; ++j) hist[j] = idxw[j * NROWS + grow];
#pragma unroll
    for (int c4 = 0; c4 < 4; ++c4){
      const int d = d0 + c4*8;
      const float* p = feat + (size_t)grow * DIM + d;
      float4 f0 = *reinterpret_cast<const float4*>(p);
      float4 f1 = *reinterpret_cast<const float4*>(p + 4);
#pragma unroll
      for (int j = 0; j < LVL; ++j){
        const float* cp = cb32 + ((size_t)j * KC + hist[j]) * DIM + d;
        const float4 c0 = *reinterpret_cast<const float4*>(cp);
        const float4 c1 = *reinterpret_cast<const float4*>(cp + 4);
        f0.x -= c0.x; f0.y -= c0.y; f0.z -= c0.z; f0.w -= c0.w;
        f1.x -= c1.x; f1.y -= c1.y; f1.z -= c1.z; f1.w -= c1.w;
      }
      bf16x8 b;
      b[0]=(short)f2b(f0.x); b[1]=(short)f2b(f0.y); b[2]=(short)f2b(f0.z); b[3]=(short)f2b(f0.w);
      b[4]=(short)f2b(f1.x); b[5]=(short)f2b(f1.y); b[6]=(short)f2b(f1.z); b[7]=(short)f2b(f1.w);
      *reinterpret_cast<bf16x8*>(&Bs[row*256 + (((d >> 3) ^ (row & 7)) << 3)]) = b;
    }
  }

  f32x4 acc[2][4];
#pragma unroll
  for (int mi = 0; mi < 2; ++mi)
#pragma unroll
    for (int ni = 0; ni < 4; ++ni) acc[mi][ni] = (f32x4){0.f,0.f,0.f,0.f};

  float t1[2] = { FLT_MAX, FLT_MAX }, t2[2] = { FLT_MAX, FLT_MAX };
  int   ti[2] = { INT_MAX, INT_MAX };

  int buf = 0;
  for (int i = 0; i < 32; ++i){
    const int ct = i >> 3, kt = i & 7;
    __syncthreads();
    {
      const int i0 = tid, r0 = i0 >> 2, c0 = i0 & 3;
      *reinterpret_cast<bf16x8*>(&As[buf*8192 + r0*32 + (c0 << 3)]) = s0;
      const int i1 = 512 + tid, r1 = i1 >> 2, c1 = i1 & 3;
      *reinterpret_cast<bf16x8*>(&As[buf*8192 + r1*32 + (c1 << 3)]) = s1;
    }
    if (i < 31){
      const int ni2 = i + 1, nct = ni2 >> 3, nkt = ni2 & 7;
#pragma unroll
      for (int it = 0; it < 2; ++it){
        const int ii = it*512 + tid, r = ii >> 2, c = ii & 3;
        const bf16x8 v = *reinterpret_cast<const bf16x8*>(
            cbb_l + (size_t)(nct*256 + r) * DIM + nkt*32 + ((c ^ (r & 3)) << 3));
        if (it == 0) s0 = v; else s1 = v;
      }
    }
    __syncthreads();

    bf16x8 Bf[2], Af[4];
#pragma unroll
    for (int mi = 0; mi < 2; ++mi){
      const int row = wr*32 + mi*16 + r16;
      Bf[mi] = *reinterpret_cast<const bf16x8*>(
          &Bs[row*256 + (((kt*4 + quad) ^ (row & 7)) << 3)]);
    }
#pragma unroll
    for (int ni = 0; ni < 4; ++ni){
      const int arow = wc*64 + ni*16 + r16;
      Af[ni] = *reinterpret_cast<const bf16x8*>(
          &As[buf*8192 + arow*32 + ((quad ^ (arow & 3)) << 3)]);
    }
#pragma unroll
    for (int ni = 0; ni < 4; ++ni){
      acc[0][ni] = __builtin_amdgcn_mfma_f32_16x16x32_bf16(Af[ni], Bf[0], acc[0][ni], 0, 0, 0);
      acc[1][ni] = __builtin_amdgcn_mfma_f32_16x16x32_bf16(Af[ni], Bf[1], acc[1][ni], 0, 0, 0);
    }

    if (kt == 7){
#pragma unroll
      for (int mi = 0; mi < 2; ++mi)
#pragma unroll
        for (int ni = 0; ni < 4; ++ni){
          const int c0 = ct*256 + wc*64 + ni*16 + quad*4;
          const float4 cn = *reinterpret_cast<const float4*>(cnx_l + c0);
          const f32x4 a = acc[mi][ni];
          const float s0v = cn.x - 2.f*a[0];
          const float s1v = cn.y - 2.f*a[1];
          const float s2v = cn.z - 2.f*a[2];
          const float s3v = cn.w - 2.f*a[3];
          upd2(t1[mi], ti[mi], t2[mi], s0v, c0+0);
          upd2(t1[mi], ti[mi], t2[mi], s1v, c0+1);
          upd2(t1[mi], ti[mi], t2[mi], s2v, c0+2);
          upd2(t1[mi], ti[mi], t2[mi], s3v, c0+3);
          const float m4 = fminf(fminf(s0v, s1v), fminf(s2v, s3v));
          const float m8 = fminf(m4, __shfl_xor(m4, 16));
          if ((quad & 1) == 0){
            const int row = wr*32 + mi*16 + r16;
            const int col = c0 >> 3;
            const __half h = __float2half(m8);
            g8s[row*128 + (col ^ ((row & 7) << 3))] =
                __builtin_bit_cast(unsigned short, h);
          }
          acc[mi][ni] = (f32x4){0.f,0.f,0.f,0.f};
        }
    }
    buf ^= 1;
  }

  __syncthreads();   // As free from here; g8s complete

  // ---- g8 write-out (coalesced) + per-wave top-2 publish ---------------
#pragma unroll
  for (int it = 0; it < 2; ++it){
    const int i = it*512 + tid;
    const int row = i >> 4, ch = i & 15;
    const uint4 v = *reinterpret_cast<const uint4*>(
        &g8s[row*128 + ((ch*8) ^ ((row & 7) << 3))]);
    *reinterpret_cast<uint4*>(g8buf + (size_t)(rowbase + row)*128 + ch*8) = v;
  }
#pragma unroll
  for (int mi = 0; mi < 2; ++mi){
    float m1 = t1[mi], m2 = t2[mi]; int i1 = ti[mi];
    merge2(m1, i1, m2, __shfl_xor(m1,16), __shfl_xor(i1,16), __shfl_xor(m2,16));
    merge2(m1, i1, m2, __shfl_xor(m1,32), __shfl_xor(i1,32), __shfl_xor(m2,32));
    if (quad == 0){
      const int row = wr*32 + mi*16 + r16;
      wm1[row*4 + wc] = m1; wi1[row*4 + wc] = i1; wm2[row*4 + wc] = m2;
    }
  }
  if (tid == 0) *acnt_s = 0;
  __syncthreads();

  // ---- per-row merge + classify ----------------------------------------
  if (tid < 64){
    float m1 = wm1[tid*4]; int i1 = wi1[tid*4]; float m2 = wm2[tid*4];
#pragma unroll
    for (int w = 1; w < 4; ++w)
      merge2(m1, i1, m2, wm1[tid*4+w], wi1[tid*4+w], wm2[tid*4+w]);
    if (m2 - m1 > AMB_MARGIN){
      idxw[LVL * NROWS + rowbase + tid] = i1;     // certain winner
    } else {
      alist[atomicAdd(acnt_s, 1)] = tid;
    }
  }
  __syncthreads();
  if (tid == 0) *abase_s = atomicAdd(&ambcnt[LVL], *acnt_s);
  __syncthreads();
  if (tid < *acnt_s) ambrows[*abase_s + tid] = rowbase + alist[tid];
}

// ---------------- K2: exact np-fp32 re-rank of AMBIGUOUS rows only ------
// verbatim r8 machinery (validated on all rows); grid-stride over amb list.
template<int LVL>
__global__ __launch_bounds__(256)
void rvq_rerank(const float* __restrict__ feat,
                const float* __restrict__ cb32,
                const float* __restrict__ cnx_l,
                int* __restrict__ idxw,
                const unsigned short* __restrict__ g8buf,
                const int* __restrict__ ambcnt,
                const int* __restrict__ ambrows)
{
  __shared__ float rres[16][260];
  __shared__ int rcnt[16];
  __shared__ int rcand[16][CAP];
  const int tid = threadIdx.x;
  const int g = tid >> 4, q = tid & 15;
  const int cnt = ambcnt[LVL];
  const float* cbl = cb32 + (size_t)LVL * KC * DIM;

  for (int rr = blockIdx.x * 16 + g; rr < cnt; rr += gridDim.x * 16){
    const int grow = ambrows[rr];
    if (q == 0) rcnt[g] = 0;

    const uint4 u = *reinterpret_cast<const uint4*>(g8buf + (size_t)grow*128 + q*8);
    const unsigned uu[4] = { u.x, u.y, u.z, u.w };
    float v[8];
#pragma unroll
    for (int e = 0; e < 8; ++e){
      const unsigned short hv = (unsigned short)(uu[e >> 1] >> ((e & 1) * 16));
      v[e] = __half2float(__builtin_bit_cast(__half, hv));
    }
    float mn = v[0];
#pragma unroll
    for (int e = 1; e < 8; ++e) mn = fminf(mn, v[e]);
#pragma unroll
    for (int m = 1; m < 16; m <<= 1) mn = fminf(mn, __shfl_xor(mn, m));
    const float thr = mn + MARGIN;

#pragma unroll
    for (int e = 0; e < 8; ++e){
      if (v[e] <= thr){
        const int pos = atomicAdd(&rcnt[g], 8);
        const int base = (q*8 + e) * 8;
#pragma unroll
        for (int e2 = 0; e2 < 8; ++e2)
          if (pos + e2 < CAP) rcand[g][pos + e2] = base + e2;
      }
    }

#pragma unroll
    for (int i4 = 0; i4 < 4; ++i4){
      const int d = q*16 + i4*4;
      float4 w = *reinterpret_cast<const float4*>(feat + (size_t)grow * DIM + d);
#pragma unroll
      for (int j2 = 0; j2 < LVL; ++j2){
        const int kj = idxw[(size_t)j2 * NROWS + grow];
        const float4 cv = *reinterpret_cast<const float4*>(
            cb32 + ((size_t)j2 * KC + kj) * DIM + d);
        w.x -= cv.x; w.y -= cv.y; w.z -= cv.z; w.w -= cv.w;
      }
      *reinterpret_cast<float4*>(&rres[g][d]) = w;
    }

    const int c = rcnt[g];
    float bs = FLT_MAX; int bi = INT_MAX;
    if (c <= CAP){
      for (int qq = q; qq < c; qq += 16){
        const int ci = rcand[g][qq];
        float a = 0.f;
        for (int d4 = 0; d4 < 64; ++d4){
          const float4 cv = *reinterpret_cast<const float4*>(cbl + (size_t)ci * DIM + d4*4);
          const float4 rv = *reinterpret_cast<const float4*>(&rres[g][d4*4]);
          a = fmaf(rv.x, cv.x, a); a = fmaf(rv.y, cv.y, a);
          a = fmaf(rv.z, cv.z, a); a = fmaf(rv.w, cv.w, a);
        }
        const float sc = cnx_l[ci] - 2.0f * a;
        if (sc < bs || (sc == bs && ci < bi)){ bs = sc; bi = ci; }
      }
    } else {
      for (int t = 0; t < 64; ++t){
        const int ci = q + 16*t;
        float a = 0.f;
        for (int d4 = 0; d4 < 64; ++d4){
          const float4 cv = *reinterpret_cast<const float4*>(cbl + (size_t)ci * DIM + d4*4);
          const float4 rv = *reinterpret_cast<const float4*>(&rres[g][d4*4]);
          a = fmaf(rv.x, cv.x, a); a = fmaf(rv.y, cv.y, a);
          a = fmaf(rv.z, cv.z, a); a = fmaf(rv.w, cv.w, a);
        }
        const float sc = cnx_l[ci] - 2.0f * a;
        if (sc < bs){ bs = sc; bi = ci; }
      }
    }
#pragma unroll
    for (int m = 1; m < 16; m <<= 1){
      const float ob = __shfl_xor(bs, m); const int oi = __shfl_xor(bi, m);
      if (ob < bs || (ob == bs && oi < bi)){ bs = ob; bi = oi; }
    }
    if (q == 0) idxw[(size_t)LVL * NROWS + grow] = bi;
  }
}

// ---------------- K3: final output = q0+q1+q2+q3 (validated r5-r8) ------
__global__ __launch_bounds__(256)
void rvq_out(const float* __restrict__ cb32,
             const int* __restrict__ idxw,
             float* __restrict__ out)
{
  const int tid = threadIdx.x;
  const int row = tid >> 4, sub = tid & 15;
  const size_t n = (size_t)blockIdx.x * 16 + row;
  int hist[NLVL];
#pragma unroll
  for (int j2 = 0; j2 < 4; ++j2) hist[j2] = idxw[(size_t)j2 * NROWS + n];
#pragma unroll
  for (int i = 0; i < 4; ++i){
    const int d = sub*4 + i*64;
    float4 a = *reinterpret_cast<const float4*>(
        cb32 + ((size_t)0 * KC + hist[0]) * DIM + d);
#pragma unroll
    for (int j2 = 1; j2 < 4; ++j2){
      const float4 qv = *reinterpret_cast<const float4*>(
          cb32 + ((size_t)j2 * KC + hist[j2]) * DIM + d);
      a.x += qv.x; a.y += qv.y; a.z += qv.z; a.w += qv.w;
    }
    *reinterpret_cast<float4*>(out + n*DIM + d) = a;
  }
}

extern "C" void kernel_launch(void* const* d_in, const int* in_sizes, int n_in,
                              void* d_out, int out_size, void* d_ws, size_t ws_size,
                              hipStream_t stream){
  const float* feat = (const float*)d_in[0];
  const float* cb32 = (const float*)d_in[1];
  float* out = (float*)d_out;

  char* ws = (char*)d_ws;
  float* cnx = (float*)(ws);                                   // 16 KB
  int*   amb = (int*)(ws + 16384);                             // 4 counters
  unsigned short* cbb  = (unsigned short*)(ws + 32768);        // 2 MB
  int*   idxw = (int*)(ws + 32768 + 2097152);                  // 2 MB
  int*   ambrows = (int*)(ws + 32768 + 2097152 + 2097152);     // 512 KB
  unsigned short* g8buf = (unsigned short*)(ws + 32768 + 2097152 + 2097152 + 524288); // 33.5 MB

  zero4<<<1, 64, 0, stream>>>(amb);
  prep_cbb<<<1024, 256, 0, stream>>>(cb32, cbb);
  prep_cn<<<64, 64, 0, stream>>>(cb32, cnx);

#define LVL_STEP(L) \
  rvq_score<L><<<2048, 512, 0, stream>>>(feat, cb32, cbb + (size_t)L*KC*DIM, \
      cnx + L*KC, idxw, g8buf, amb, ambrows); \
  rvq_rerank<L><<<1024, 256, 0, stream>>>(feat, cb32, cnx + L*KC, idxw, g8buf, amb, ambrows);

  LVL_STEP(0)
  LVL_STEP(1)
  LVL_STEP(2)
  LVL_STEP(3)
#undef LVL_STEP

  rvq_out<<<8192, 256, 0, stream>>>(cb32, idxw, out);
}